// Round 1
// baseline (1091.261 us; speedup 1.0000x reference)
//
#include <hip/hip_runtime.h>
#include <math.h>

#define Nn 80000
#define Dd 1000
#define KP 1024
#define Ee 1280000
#define MM 64000

typedef __attribute__((ext_vector_type(8))) short bf16x8;
typedef __attribute__((ext_vector_type(4))) float f32x4;

__device__ inline unsigned short f2bf(float f){
  union { float f; unsigned u; } c; c.f = f;
  unsigned u = c.u;
  u += 0x7FFFu + ((u >> 16) & 1u);
  return (unsigned short)(u >> 16);
}

// ---------------- init: W1 -> bf16 transposed/padded, zero flags/deg/loss ---
__global__ __launch_bounds__(256) void k_init(const float* __restrict__ W1,
    unsigned short* __restrict__ W1t, int* __restrict__ flags,
    int* __restrict__ deg, float* __restrict__ loss)
{
  int i = blockIdx.x*256 + threadIdx.x;
  if (i < 64*KP){
    int n = i >> 10, k = i & (KP-1);
    W1t[i] = (k < Dd) ? f2bf(W1[k*64 + n]) : (unsigned short)0;
  }
  if (i < Nn){ flags[i] = 0; deg[i] = 0; }
  if (i == 0) *loss = 0.f;
}

// ---------------- scatter mask flags + degree histogram ---------------------
__global__ __launch_bounds__(256) void k_scatter(const int* __restrict__ mask,
    const int* __restrict__ rows, int* __restrict__ flags, int* __restrict__ deg)
{
  int i = blockIdx.x*256 + threadIdx.x;
  if (i < MM) flags[mask[i]] = 1;
  if (i < Ee) atomicAdd(&deg[rows[i]], 1);
}

// ---------------- exclusive scan (single block, segmented) ------------------
__global__ __launch_bounds__(256) void k_scan(const int* __restrict__ deg,
    int* __restrict__ rstart, int* __restrict__ cursor)
{
  __shared__ int sums[256];
  __shared__ int pref[257];
  const int SEG = (Nn + 255) / 256;   // 313
  int t = threadIdx.x;
  int lo = t*SEG, hi = lo + SEG; if (hi > Nn) hi = Nn;
  int s = 0;
  for (int i = lo; i < hi; ++i) s += deg[i];
  sums[t] = s;
  __syncthreads();
  if (t == 0){
    int r = 0;
    for (int j = 0; j < 256; ++j){ pref[j] = r; r += sums[j]; }
    pref[256] = r;
  }
  __syncthreads();
  int off = pref[t];
  for (int i = lo; i < hi; ++i){
    rstart[i] = off; cursor[i] = off; off += deg[i];
  }
  if (t == 0) rstart[Nn] = pref[256];
}

// ---------------- CSR fill --------------------------------------------------
__global__ __launch_bounds__(256) void k_fill(const int* __restrict__ rows,
    const int* __restrict__ cols, const float* __restrict__ vals,
    int* __restrict__ cursor, int* __restrict__ csrc, float* __restrict__ csrv)
{
  int e = blockIdx.x*256 + threadIdx.x;
  if (e >= Ee) return;
  int r = rows[e];
  int p = atomicAdd(&cursor[r], 1);
  csrc[p] = cols[e]; csrv[p] = vals[e];
}

// ---------------- GEMM1: h = elu(bn(out_x @ W1 + b1)), bf16 MFMA ------------
__global__ __launch_bounds__(256) void k_gemm1(
    const float* __restrict__ x, const unsigned short* __restrict__ W1t,
    const int* __restrict__ flags, const float* __restrict__ token,
    const float* __restrict__ b1, const float* __restrict__ g1,
    const float* __restrict__ be1, const float* __restrict__ rm1,
    const float* __restrict__ rv1, float* __restrict__ h)
{
  __shared__ unsigned short As[128*40];
  __shared__ unsigned short Bs[64*40];
  const int tid  = threadIdx.x;
  const int lane = tid & 63;
  const int wave = tid >> 6;
  const int wm = wave >> 1, wn = wave & 1;
  const int row0 = blockIdx.x * 128;

  const int kq    = (tid & 7) * 4;
  const int rbase = tid >> 3;
  const float* xp[4]; int fl[4];
  #pragma unroll
  for (int it = 0; it < 4; ++it){
    int r = it*32 + rbase;
    xp[it] = x + (size_t)(row0 + r) * Dd;
    fl[it] = flags[row0 + r];
  }
  const int bn_ = tid >> 2;
  const int bp_ = (tid & 3) * 8;

  const f32x4 zero4 = {0.f,0.f,0.f,0.f};
  f32x4 acc[4][2];
  #pragma unroll
  for (int i = 0; i < 4; ++i){ acc[i][0] = zero4; acc[i][1] = zero4; }

  for (int k0 = 0; k0 < KP; k0 += 32){
    #pragma unroll
    for (int it = 0; it < 4; ++it){
      int r = it*32 + rbase;
      int k = k0 + kq;
      float v0, v1, v2, v3;
      if (k + 3 < Dd){
        f32x4 v = *reinterpret_cast<const f32x4*>(xp[it] + k);
        v0 = v.x; v1 = v.y; v2 = v.z; v3 = v.w;
        if (fl[it]){
          f32x4 tk = *reinterpret_cast<const f32x4*>(token + k);
          v0 += tk.x; v1 += tk.y; v2 += tk.z; v3 += tk.w;
        }
      } else {
        v0 = (k   < Dd) ? (xp[it][k  ] + (fl[it] ? token[k  ] : 0.f)) : 0.f;
        v1 = (k+1 < Dd) ? (xp[it][k+1] + (fl[it] ? token[k+1] : 0.f)) : 0.f;
        v2 = (k+2 < Dd) ? (xp[it][k+2] + (fl[it] ? token[k+2] : 0.f)) : 0.f;
        v3 = (k+3 < Dd) ? (xp[it][k+3] + (fl[it] ? token[k+3] : 0.f)) : 0.f;
      }
      unsigned short* dst = &As[r*40 + kq];
      dst[0] = f2bf(v0); dst[1] = f2bf(v1); dst[2] = f2bf(v2); dst[3] = f2bf(v3);
    }
    *reinterpret_cast<bf16x8*>(&Bs[bn_*40 + bp_]) =
        *reinterpret_cast<const bf16x8*>(&W1t[bn_*KP + k0 + bp_]);
    __syncthreads();

    bf16x8 bfr[2];
    #pragma unroll
    for (int ni = 0; ni < 2; ++ni){
      int c = wn*32 + ni*16 + (lane & 15);
      bfr[ni] = *reinterpret_cast<const bf16x8*>(&Bs[c*40 + (lane>>4)*8]);
    }
    #pragma unroll
    for (int mi = 0; mi < 4; ++mi){
      int r = wm*64 + mi*16 + (lane & 15);
      bf16x8 af = *reinterpret_cast<const bf16x8*>(&As[r*40 + (lane>>4)*8]);
      acc[mi][0] = __builtin_amdgcn_mfma_f32_16x16x32_bf16(af, bfr[0], acc[mi][0], 0, 0, 0);
      acc[mi][1] = __builtin_amdgcn_mfma_f32_16x16x32_bf16(af, bfr[1], acc[mi][1], 0, 0, 0);
    }
    __syncthreads();
  }

  #pragma unroll
  for (int ni = 0; ni < 2; ++ni){
    int n = wn*32 + ni*16 + (lane & 15);
    float bb = b1[n], rm = rm1[n], sc = g1[n]*rsqrtf(rv1[n] + 1e-3f), be = be1[n];
    #pragma unroll
    for (int mi = 0; mi < 4; ++mi){
      #pragma unroll
      for (int r4 = 0; r4 < 4; ++r4){
        int m = row0 + wm*64 + mi*16 + (lane>>4)*4 + r4;
        float v = (acc[mi][ni][r4] + bb - rm)*sc + be;
        v = (v > 0.f) ? v : expm1f(v);
        h[(size_t)m*64 + n] = v;
      }
    }
  }
}

// ---------------- GEMM2: feat_x = elu(bn(h @ W2 + b2)) ----------------------
__global__ __launch_bounds__(256) void k_gemm2(const float* __restrict__ h,
    const float* __restrict__ W2, const float* __restrict__ b2,
    const float* __restrict__ g2, const float* __restrict__ be2,
    const float* __restrict__ rm2, const float* __restrict__ rv2,
    float* __restrict__ fx)
{
  int i = blockIdx.x*256 + threadIdx.x;
  if (i >= Nn*16) return;
  int row = i >> 4, j = i & 15;
  float acc = b2[j];
  const float* hr = h + (size_t)row*64;
  #pragma unroll
  for (int k = 0; k < 64; ++k) acc += hr[k]*W2[k*16 + j];
  float v = (acc - rm2[j])*(g2[j]*rsqrtf(rv2[j] + 1e-3f)) + be2[j];
  fx[i] = (v > 0.f) ? v : expm1f(v);
}

// ---------------- t1 = feat_x @ Wgc1 ----------------------------------------
__global__ __launch_bounds__(256) void k_t1(const float* __restrict__ fx,
    const float* __restrict__ Wgc1, float* __restrict__ t1)
{
  int i = blockIdx.x*256 + threadIdx.x;
  if (i >= Nn*64) return;
  int row = i >> 6, j = i & 63;
  const float* fr = fx + (size_t)row*16;
  float acc = 0.f;
  #pragma unroll
  for (int k = 0; k < 16; ++k) acc += fr[k]*Wgc1[k*64 + j];
  t1[i] = acc;
}

// ---------------- SpMM F=64 (CSR, wave per row) ------------------------------
template<bool RELU>
__global__ __launch_bounds__(256) void k_spmm64(const int* __restrict__ rstart,
    const int* __restrict__ csrc, const float* __restrict__ csrv,
    const float* __restrict__ in, float* __restrict__ out)
{
  int row = blockIdx.x*4 + (threadIdx.x >> 6);
  int lane = threadIdx.x & 63;
  if (row >= Nn) return;
  int s = rstart[row], e = rstart[row+1];
  float acc = 0.f;
  for (int p = s; p < e; ++p){
    int c = csrc[p]; float v = csrv[p];
    acc += v * in[(size_t)c*64 + lane];
  }
  if (RELU) acc = fmaxf(acc, 0.f);
  out[(size_t)row*64 + lane] = acc;
}

// ---------------- mu/logvar/z/gnn_z from ah ---------------------------------
__global__ __launch_bounds__(256) void k_mulv(const float* __restrict__ ah,
    const float* __restrict__ Wgc2, const float* __restrict__ Wgc3,
    const float* __restrict__ fx, float* __restrict__ z, float* __restrict__ mu,
    float* __restrict__ lv, float* __restrict__ gz)
{
  int i = blockIdx.x*256 + threadIdx.x;
  if (i >= Nn*16) return;
  int row = i >> 4, j = i & 15;
  const float* ar = ah + (size_t)row*64;
  float m = 0.f, l = 0.f;
  #pragma unroll
  for (int k = 0; k < 64; ++k){
    float a = ar[k];
    m += a*Wgc2[k*16 + j];
    l += a*Wgc3[k*16 + j];
  }
  mu[i] = m; lv[i] = l; gz[i] = m;
  z[(size_t)row*32 + 16 + j] = m;
  z[(size_t)row*32 + j] = fx[i];
}

// ---------------- SpMM F=32 -------------------------------------------------
__global__ __launch_bounds__(256) void k_spmm32(const int* __restrict__ rstart,
    const int* __restrict__ csrc, const float* __restrict__ csrv,
    const float* __restrict__ z, float* __restrict__ az)
{
  int row = blockIdx.x*8 + (threadIdx.x >> 5);
  int lane = threadIdx.x & 31;
  if (row >= Nn) return;
  int s = rstart[row], e = rstart[row+1];
  float acc = 0.f;
  for (int p = s; p < e; ++p)
    acc += csrv[p] * z[(size_t)csrc[p]*32 + lane];
  az[(size_t)row*32 + lane] = acc;
}

// ---------------- decoder: de = az @ Wdec ------------------------------------
__global__ __launch_bounds__(256) void k_dec(const float* __restrict__ az,
    const float* __restrict__ Wdec, float* __restrict__ de)
{
  __shared__ float azT[32][36];
  __shared__ float WL[32][132];
  const int tid = threadIdx.x;
  const int r0 = blockIdx.x * 32;
  {
    int r = tid >> 3, kq = (tid & 7) * 4;
    f32x4 v = *reinterpret_cast<const f32x4*>(&az[(size_t)(r0 + r)*32 + kq]);
    azT[kq+0][r] = v.x; azT[kq+1][r] = v.y; azT[kq+2][r] = v.z; azT[kq+3][r] = v.w;
  }
  const int rg = tid >> 5, cg = tid & 31;
  for (int c0 = 0; c0 < 1000; c0 += 128){
    int rem = 1000 - c0; if (rem > 128) rem = 128;
    __syncthreads();
    #pragma unroll
    for (int it = 0; it < 4; ++it){
      int L = it*256 + tid;
      int k = L >> 5, c4 = (L & 31) * 4;
      f32x4 v = {0.f,0.f,0.f,0.f};
      if (c4 < rem) v = *reinterpret_cast<const f32x4*>(&Wdec[(size_t)k*1000 + c0 + c4]);
      *reinterpret_cast<f32x4*>(&WL[k][c4]) = v;
    }
    __syncthreads();
    if (cg*4 < rem){
      f32x4 a0 = {0.f,0.f,0.f,0.f}, a1 = a0, a2 = a0, a3 = a0;
      #pragma unroll
      for (int k = 0; k < 32; ++k){
        f32x4 w = *reinterpret_cast<const f32x4*>(&WL[k][cg*4]);
        f32x4 a = *reinterpret_cast<const f32x4*>(&azT[k][rg*4]);
        a0 += a.x * w; a1 += a.y * w; a2 += a.z * w; a3 += a.w * w;
      }
      size_t base = (size_t)(r0 + rg*4)*1000 + c0 + cg*4;
      *reinterpret_cast<f32x4*>(&de[base       ]) = a0;
      *reinterpret_cast<f32x4*>(&de[base + 1000]) = a1;
      *reinterpret_cast<f32x4*>(&de[base + 2000]) = a2;
      *reinterpret_cast<f32x4*>(&de[base + 3000]) = a3;
    }
  }
}

// ---------------- q (student-t, alpha=1 => exponent 1) ----------------------
__global__ __launch_bounds__(256) void k_q(const float* __restrict__ z,
    const float* __restrict__ cl, float* __restrict__ q)
{
  __shared__ float cls[320];
  int t = threadIdx.x;
  for (int i = t; i < 320; i += 256) cls[i] = cl[i];
  __syncthreads();
  int row = blockIdx.x*256 + t;
  if (row >= Nn) return;
  float zr[32];
  #pragma unroll
  for (int i = 0; i < 8; ++i){
    f32x4 v = *reinterpret_cast<const f32x4*>(&z[(size_t)row*32 + i*4]);
    zr[i*4] = v.x; zr[i*4+1] = v.y; zr[i*4+2] = v.z; zr[i*4+3] = v.w;
  }
  float qs[10], s = 0.f;
  #pragma unroll
  for (int c = 0; c < 10; ++c){
    float d2 = 0.f;
    #pragma unroll
    for (int k = 0; k < 32; ++k){ float d = zr[k] - cls[c*32 + k]; d2 += d*d; }
    float qq = 1.f/(1.f + d2);
    qs[c] = qq; s += qq;
  }
  float inv = 1.f/s;
  #pragma unroll
  for (int c = 0; c < 10; ++c) q[(size_t)row*10 + c] = qs[c]*inv;
}

// ---------------- loss: per-masked-node term ---------------------------------
__global__ __launch_bounds__(256) void k_loss(const float* __restrict__ de,
    const float* __restrict__ x, const float* __restrict__ token,
    const int* __restrict__ mask, float* __restrict__ term)
{
  int w = blockIdx.x*4 + (threadIdx.x >> 6);
  int lane = threadIdx.x & 63;
  if (w >= MM) return;
  int node = mask[w];
  const float* xr = de + (size_t)node*Dd;
  const float* xi = x  + (size_t)node*Dd;
  float srr = 0.f, sii = 0.f, sri = 0.f;
  #pragma unroll 3
  for (int it = 0; it < 15; ++it){
    int idx = it*64 + lane;
    float r = xr[idx], v = xi[idx] + token[idx];
    srr += r*r; sii += v*v; sri += r*v;
  }
  {
    int idx = 960 + lane;
    if (idx < Dd){
      float r = xr[idx], v = xi[idx] + token[idx];
      srr += r*r; sii += v*v; sri += r*v;
    }
  }
  #pragma unroll
  for (int o = 32; o; o >>= 1){
    srr += __shfl_down(srr, o);
    sii += __shfl_down(sii, o);
    sri += __shfl_down(sri, o);
  }
  if (lane == 0){
    float nr = fmaxf(sqrtf(srr), 1e-12f), ni = fmaxf(sqrtf(sii), 1e-12f);
    float tt = 1.f - sri/(nr*ni);
    term[w] = tt*tt*tt;
  }
}

__global__ __launch_bounds__(1024) void k_loss_sum(const float* __restrict__ term,
    float* __restrict__ loss)
{
  __shared__ float red[1024];
  int t = threadIdx.x;
  float s = 0.f;
  for (int i = t; i < MM; i += 1024) s += term[i];
  red[t] = s; __syncthreads();
  for (int o = 512; o; o >>= 1){ if (t < o) red[t] += red[t + o]; __syncthreads(); }
  if (t == 0) *loss = red[0] * (1.f/MM);
}

// ---------------- launch -----------------------------------------------------
extern "C" void kernel_launch(void* const* d_in, const int* in_sizes, int n_in,
                              void* d_out, int out_size, void* d_ws, size_t ws_size,
                              hipStream_t stream)
{
  const float* x     = (const float*)d_in[0];
  const int*   erow  = (const int*)  d_in[1];
  const int*   ecol  = (const int*)  d_in[2];
  const float* evls  = (const float*)d_in[3];
  const int*   mask  = (const int*)  d_in[4];
  const float* token = (const float*)d_in[5];
  const float* W1  = (const float*)d_in[6];
  const float* b1  = (const float*)d_in[7];
  const float* g1  = (const float*)d_in[8];
  const float* be1 = (const float*)d_in[9];
  const float* rm1 = (const float*)d_in[10];
  const float* rv1 = (const float*)d_in[11];
  const float* W2  = (const float*)d_in[12];
  const float* b2  = (const float*)d_in[13];
  const float* g2  = (const float*)d_in[14];
  const float* be2 = (const float*)d_in[15];
  const float* rm2 = (const float*)d_in[16];
  const float* rv2 = (const float*)d_in[17];
  const float* Wgc1= (const float*)d_in[18];
  const float* Wgc2= (const float*)d_in[19];
  const float* Wgc3= (const float*)d_in[20];
  const float* Wdec= (const float*)d_in[21];
  const float* clus= (const float*)d_in[22];

  float* out = (float*)d_out;
  float* oz  = out;
  float* omu = out + (size_t)Nn*32;
  float* olv = omu + (size_t)Nn*16;
  float* ode = olv + (size_t)Nn*16;
  float* oq  = ode + (size_t)Nn*1000;
  float* ofx = oq  + (size_t)Nn*10;
  float* ogz = ofx + (size_t)Nn*16;
  float* olo = ogz + (size_t)Nn*16;

  char* w = (char*)d_ws;
  unsigned short* W1t = (unsigned short*)w; w += (size_t)64*KP*2;
  int* flags  = (int*)w;   w += (size_t)Nn*4;
  int* deg    = (int*)w;   w += (size_t)Nn*4;
  int* rstart = (int*)w;   w += (size_t)(Nn+2)*4;
  int* cursor = (int*)w;   w += (size_t)Nn*4;
  int* csrc   = (int*)w;   w += (size_t)Ee*4;
  float* csrv = (float*)w; w += (size_t)Ee*4;
  float* buf0 = (float*)w; w += (size_t)Nn*64*4;   // h, then ah
  float* buf1 = (float*)w; w += (size_t)Nn*64*4;   // t1, then az
  float* buf2 = (float*)w; w += (size_t)Nn*64*4;   // hidden1
  float* term = (float*)w; w += (size_t)MM*4;

  k_init<<<dim3(313), dim3(256), 0, stream>>>(W1, W1t, flags, deg, olo);
  k_scatter<<<dim3((Ee+255)/256), dim3(256), 0, stream>>>(mask, erow, flags, deg);
  k_scan<<<dim3(1), dim3(256), 0, stream>>>(deg, rstart, cursor);
  k_fill<<<dim3((Ee+255)/256), dim3(256), 0, stream>>>(erow, ecol, evls, cursor, csrc, csrv);
  k_gemm1<<<dim3(Nn/128), dim3(256), 0, stream>>>(x, W1t, flags, token, b1, g1, be1, rm1, rv1, buf0);
  k_gemm2<<<dim3((Nn*16+255)/256), dim3(256), 0, stream>>>(buf0, W2, b2, g2, be2, rm2, rv2, ofx);
  k_t1<<<dim3((Nn*64+255)/256), dim3(256), 0, stream>>>(ofx, Wgc1, buf1);
  k_spmm64<true><<<dim3(Nn/4), dim3(256), 0, stream>>>(rstart, csrc, csrv, buf1, buf2);
  k_spmm64<false><<<dim3(Nn/4), dim3(256), 0, stream>>>(rstart, csrc, csrv, buf2, buf0);
  k_mulv<<<dim3((Nn*16+255)/256), dim3(256), 0, stream>>>(buf0, Wgc2, Wgc3, ofx, oz, omu, olv, ogz);
  k_spmm32<<<dim3(Nn/8), dim3(256), 0, stream>>>(rstart, csrc, csrv, oz, buf1);
  k_dec<<<dim3(Nn/32), dim3(256), 0, stream>>>(buf1, Wdec, ode);
  k_q<<<dim3((Nn+255)/256), dim3(256), 0, stream>>>(oz, clus, oq);
  k_loss<<<dim3(MM/4), dim3(256), 0, stream>>>(ode, x, token, mask, term);
  k_loss_sum<<<dim3(1), dim3(1024), 0, stream>>>(term, olo);
}

// Round 2
// 769.882 us; speedup vs baseline: 1.4174x; 1.4174x over previous
//
#include <hip/hip_runtime.h>
#include <math.h>

#define Nn 80000
#define Dd 1000
#define KP 1024
#define Ee 1280000
#define MM 64000
#define SB 1024
#define NB 79   // ceil(Nn/SB)

typedef __attribute__((ext_vector_type(8))) short bf16x8;
typedef __attribute__((ext_vector_type(4))) short bf16x4;
typedef __attribute__((ext_vector_type(4))) float f32x4;
typedef __attribute__((ext_vector_type(4))) int i32x4;

__device__ inline unsigned short f2bf(float f){
  union { float f; unsigned u; } c; c.f = f;
  unsigned u = c.u;
  u += 0x7FFFu + ((u >> 16) & 1u);
  return (unsigned short)(u >> 16);
}

// ---------------- init: W1->bf16^T padded, tw=token@W1, zero flags/deg ------
__global__ __launch_bounds__(256) void k_init(const float* __restrict__ W1,
    const float* __restrict__ token, unsigned short* __restrict__ W1t,
    float* __restrict__ tw, int* __restrict__ flags, int* __restrict__ deg)
{
  int i = blockIdx.x*256 + threadIdx.x;
  if (i < 64*KP){
    int n = i >> 10, k = i & (KP-1);
    W1t[i] = (k < Dd) ? f2bf(W1[k*64 + n]) : (unsigned short)0;
  }
  if (i < Nn){ flags[i] = 0; deg[i] = 0; }
  if (i < 64){
    float s = 0.f;
    for (int k = 0; k < Dd; ++k) s += token[k]*W1[k*64 + i];
    tw[i] = s;
  }
}

// ---------------- scatter mask flags + degree histogram ---------------------
__global__ __launch_bounds__(256) void k_scatter(const int* __restrict__ mask,
    const int* __restrict__ rows, int* __restrict__ flags, int* __restrict__ deg)
{
  int i = blockIdx.x*256 + threadIdx.x;
  if (i < MM) flags[mask[i]] = 1;
  if (i < Ee) atomicAdd(&deg[rows[i]], 1);
}

// ---------------- hierarchical scan ------------------------------------------
__global__ __launch_bounds__(256) void k_scan1(const int* __restrict__ deg,
    int* __restrict__ bsum)
{
  int base = blockIdx.x*SB + threadIdx.x*4;
  int s = 0;
  if (base + 3 < Nn){
    i32x4 v = *reinterpret_cast<const i32x4*>(&deg[base]);
    s = v.x + v.y + v.z + v.w;
  } else {
    for (int j = 0; j < 4; ++j) if (base + j < Nn) s += deg[base + j];
  }
  #pragma unroll
  for (int o = 32; o; o >>= 1) s += __shfl_down(s, o);
  __shared__ int red[4];
  if ((threadIdx.x & 63) == 0) red[threadIdx.x >> 6] = s;
  __syncthreads();
  if (threadIdx.x == 0) bsum[blockIdx.x] = red[0] + red[1] + red[2] + red[3];
}

__global__ __launch_bounds__(128) void k_scan2(int* __restrict__ bsum,
    int* __restrict__ rstart)
{
  __shared__ int sh[NB];
  int t = threadIdx.x;
  if (t < NB) sh[t] = bsum[t];
  __syncthreads();
  if (t == 0){
    int r = 0;
    for (int j = 0; j < NB; ++j){ int v = sh[j]; sh[j] = r; r += v; }
    rstart[Nn] = r;
  }
  __syncthreads();
  if (t < NB) bsum[t] = sh[t];
}

__global__ __launch_bounds__(256) void k_scan3(const int* __restrict__ deg,
    const int* __restrict__ bsum, int* __restrict__ rstart, int* __restrict__ cursor)
{
  __shared__ int tsum[256];
  __shared__ int pref[256];
  int t = threadIdx.x;
  int base = blockIdx.x*SB + t*4;
  int d0=0,d1=0,d2=0,d3=0;
  if (base + 3 < Nn){
    i32x4 v = *reinterpret_cast<const i32x4*>(&deg[base]);
    d0=v.x; d1=v.y; d2=v.z; d3=v.w;
  } else {
    if (base   < Nn) d0 = deg[base];
    if (base+1 < Nn) d1 = deg[base+1];
    if (base+2 < Nn) d2 = deg[base+2];
    if (base+3 < Nn) d3 = deg[base+3];
  }
  tsum[t] = d0+d1+d2+d3;
  __syncthreads();
  if (t == 0){
    int r = 0;
    for (int j = 0; j < 256; ++j){ pref[j] = r; r += tsum[j]; }
  }
  __syncthreads();
  int off = pref[t] + bsum[blockIdx.x];
  int o0 = off, o1 = off+d0, o2 = off+d0+d1, o3 = off+d0+d1+d2;
  if (base + 3 < Nn){
    i32x4 w; w.x=o0; w.y=o1; w.z=o2; w.w=o3;
    *reinterpret_cast<i32x4*>(&rstart[base]) = w;
    *reinterpret_cast<i32x4*>(&cursor[base]) = w;
  } else {
    if (base   < Nn){ rstart[base]=o0;   cursor[base]=o0; }
    if (base+1 < Nn){ rstart[base+1]=o1; cursor[base+1]=o1; }
    if (base+2 < Nn){ rstart[base+2]=o2; cursor[base+2]=o2; }
    if (base+3 < Nn){ rstart[base+3]=o3; cursor[base+3]=o3; }
  }
}

// ---------------- CSR fill --------------------------------------------------
__global__ __launch_bounds__(256) void k_fill(const int* __restrict__ rows,
    const int* __restrict__ cols, const float* __restrict__ vals,
    int* __restrict__ cursor, int* __restrict__ csrc, float* __restrict__ csrv)
{
  int e = blockIdx.x*256 + threadIdx.x;
  if (e >= Ee) return;
  int r = rows[e];
  int p = atomicAdd(&cursor[r], 1);
  csrc[p] = cols[e]; csrv[p] = vals[e];
}

// ---------------- GEMM1 (+fused encoder L2): fx = enc(x) --------------------
__global__ __launch_bounds__(256) void k_gemm1(
    const float* __restrict__ x, const unsigned short* __restrict__ W1t,
    const int* __restrict__ flags, const float* __restrict__ tw,
    const float* __restrict__ b1, const float* __restrict__ g1,
    const float* __restrict__ be1, const float* __restrict__ rm1,
    const float* __restrict__ rv1, const float* __restrict__ W2,
    const float* __restrict__ b2, const float* __restrict__ g2,
    const float* __restrict__ be2, const float* __restrict__ rm2,
    const float* __restrict__ rv2, float* __restrict__ fx)
{
  __shared__ char smem[37888];
  unsigned short* As = (unsigned short*)smem;            // 128*40*2 = 10240
  unsigned short* Bs = (unsigned short*)(smem + 10240);  // 64*40*2  = 5120
  float* Hs  = (float*)smem;                             // 128*66*4 = 33792
  float* W2s = (float*)(smem + 33792);                   // 64*16*4  = 4096

  const int tid  = threadIdx.x;
  const int lane = tid & 63;
  const int wave = tid >> 6;
  const int wm = wave >> 1, wn = wave & 1;
  const int row0 = blockIdx.x * 128;

  // stage W2 (region does not overlap As/Bs)
  #pragma unroll
  for (int t = tid; t < 1024; t += 256) W2s[t] = W2[t];

  const int kq    = (tid & 7) * 4;
  const int rbase = tid >> 3;
  const float* xp[4];
  #pragma unroll
  for (int it = 0; it < 4; ++it)
    xp[it] = x + (size_t)(row0 + it*32 + rbase) * Dd;

  const int bn_ = tid >> 2;
  const int bp_ = (tid & 3) * 8;

  const f32x4 zero4 = {0.f,0.f,0.f,0.f};
  f32x4 acc[4][2];
  #pragma unroll
  for (int i = 0; i < 4; ++i){ acc[i][0] = zero4; acc[i][1] = zero4; }

  for (int k0 = 0; k0 < KP; k0 += 32){
    int k = k0 + kq;
    #pragma unroll
    for (int it = 0; it < 4; ++it){
      bf16x4 pk;
      if (k < Dd){   // Dd%4==0 and k%4==0 -> full vector or nothing
        f32x4 v = *reinterpret_cast<const f32x4*>(xp[it] + k);
        pk[0] = (short)f2bf(v.x); pk[1] = (short)f2bf(v.y);
        pk[2] = (short)f2bf(v.z); pk[3] = (short)f2bf(v.w);
      } else { pk[0]=0; pk[1]=0; pk[2]=0; pk[3]=0; }
      *reinterpret_cast<bf16x4*>(&As[(it*32 + rbase)*40 + kq]) = pk;
    }
    *reinterpret_cast<bf16x8*>(&Bs[bn_*40 + bp_]) =
        *reinterpret_cast<const bf16x8*>(&W1t[bn_*KP + k0 + bp_]);
    __syncthreads();

    bf16x8 bfr[2];
    #pragma unroll
    for (int ni = 0; ni < 2; ++ni){
      int c = wn*32 + ni*16 + (lane & 15);
      bfr[ni] = *reinterpret_cast<const bf16x8*>(&Bs[c*40 + (lane>>4)*8]);
    }
    #pragma unroll
    for (int mi = 0; mi < 4; ++mi){
      int r = wm*64 + mi*16 + (lane & 15);
      bf16x8 af = *reinterpret_cast<const bf16x8*>(&As[r*40 + (lane>>4)*8]);
      acc[mi][0] = __builtin_amdgcn_mfma_f32_16x16x32_bf16(af, bfr[0], acc[mi][0], 0, 0, 0);
      acc[mi][1] = __builtin_amdgcn_mfma_f32_16x16x32_bf16(af, bfr[1], acc[mi][1], 0, 0, 0);
    }
    __syncthreads();
  }

  // epilogue: BN1 + ELU -> Hs (LDS)
  float bb[2], rmv[2], scv[2], bev[2], twn[2]; int nn[2];
  #pragma unroll
  for (int ni = 0; ni < 2; ++ni){
    int n = wn*32 + ni*16 + (lane & 15);
    nn[ni] = n;
    bb[ni] = b1[n]; rmv[ni] = rm1[n];
    scv[ni] = g1[n]*rsqrtf(rv1[n] + 1e-3f); bev[ni] = be1[n];
    twn[ni] = tw[n];
  }
  #pragma unroll
  for (int mi = 0; mi < 4; ++mi){
    #pragma unroll
    for (int r4 = 0; r4 < 4; ++r4){
      int lrow = wm*64 + mi*16 + (lane>>4)*4 + r4;
      float fl = flags[row0 + lrow] ? 1.f : 0.f;
      #pragma unroll
      for (int ni = 0; ni < 2; ++ni){
        float v = (acc[mi][ni][r4] + bb[ni] + fl*twn[ni] - rmv[ni])*scv[ni] + bev[ni];
        v = (v > 0.f) ? v : expm1f(v);
        Hs[lrow*66 + nn[ni]] = v;
      }
    }
  }
  __syncthreads();

  // phase 2: fx = elu(bn2(Hs @ W2 + b2)), 128x16 outputs
  {
    int j = tid & 15;
    float pb = b2[j], prm = rm2[j];
    float psc = g2[j]*rsqrtf(rv2[j] + 1e-3f), pbe = be2[j];
    int rb = (tid >> 4) * 8;
    #pragma unroll
    for (int rr = 0; rr < 8; ++rr){
      int r = rb + rr;
      float a = pb;
      #pragma unroll
      for (int k = 0; k < 64; ++k) a += Hs[r*66 + k]*W2s[k*16 + j];
      float v = (a - prm)*psc + pbe;
      v = (v > 0.f) ? v : expm1f(v);
      fx[(size_t)(row0 + r)*16 + j] = v;
    }
  }
}

// ---------------- SpMM F=16: afx = A @ fx ------------------------------------
__global__ __launch_bounds__(256) void k_spmm16(const int* __restrict__ rstart,
    const int* __restrict__ csrc, const float* __restrict__ csrv,
    const float* __restrict__ fx, float* __restrict__ afx)
{
  int row = blockIdx.x*16 + (threadIdx.x >> 4);
  int l = threadIdx.x & 15;
  if (row >= Nn) return;
  int s = rstart[row], e = rstart[row+1];
  float acc = 0.f;
  for (int p = s; p < e; ++p)
    acc += csrv[p] * fx[(size_t)csrc[p]*16 + l];
  afx[(size_t)row*16 + l] = acc;
}

// ---------------- h1 = relu(afx @ Wgc1) --------------------------------------
__global__ __launch_bounds__(256) void k_h1(const float* __restrict__ afx,
    const float* __restrict__ Wgc1, float* __restrict__ h1)
{
  __shared__ float Ws[16*64];
  for (int t = threadIdx.x; t < 1024; t += 256) Ws[t] = Wgc1[t];
  __syncthreads();
  int i = blockIdx.x*256 + threadIdx.x;
  if (i >= Nn*64) return;
  int row = i >> 6, j = i & 63;
  const float* ar = afx + (size_t)row*16;
  float acc = 0.f;
  #pragma unroll
  for (int k = 0; k < 16; ++k) acc += ar[k]*Ws[k*64 + j];
  h1[i] = fmaxf(acc, 0.f);
}

// ---------------- SpMM F=64: ah = A @ h1 -------------------------------------
__global__ __launch_bounds__(256) void k_spmm64(const int* __restrict__ rstart,
    const int* __restrict__ csrc, const float* __restrict__ csrv,
    const float* __restrict__ in, float* __restrict__ out)
{
  int row = blockIdx.x*4 + (threadIdx.x >> 6);
  int lane = threadIdx.x & 63;
  if (row >= Nn) return;
  int s = rstart[row], e = rstart[row+1];
  float acc = 0.f;
  for (int p = s; p < e; ++p)
    acc += csrv[p] * in[(size_t)csrc[p]*64 + lane];
  out[(size_t)row*64 + lane] = acc;
}

// ---------------- mu/logvar/z/gnn_z from ah ---------------------------------
__global__ __launch_bounds__(256) void k_mulv(const float* __restrict__ ah,
    const float* __restrict__ Wgc2, const float* __restrict__ Wgc3,
    const float* __restrict__ fx, float* __restrict__ z, float* __restrict__ mu,
    float* __restrict__ lv, float* __restrict__ gz)
{
  int i = blockIdx.x*256 + threadIdx.x;
  if (i >= Nn*16) return;
  int row = i >> 4, j = i & 15;
  const float* ar = ah + (size_t)row*64;
  float m = 0.f, l = 0.f;
  #pragma unroll
  for (int k = 0; k < 64; ++k){
    float a = ar[k];
    m += a*Wgc2[k*16 + j];
    l += a*Wgc3[k*16 + j];
  }
  mu[i] = m; lv[i] = l; gz[i] = m;
  z[(size_t)row*32 + 16 + j] = m;
  z[(size_t)row*32 + j] = fx[i];
}

// ---------------- SpMM F=32: az = A @ z --------------------------------------
__global__ __launch_bounds__(256) void k_spmm32(const int* __restrict__ rstart,
    const int* __restrict__ csrc, const float* __restrict__ csrv,
    const float* __restrict__ z, float* __restrict__ az)
{
  int row = blockIdx.x*8 + (threadIdx.x >> 5);
  int lane = threadIdx.x & 31;
  if (row >= Nn) return;
  int s = rstart[row], e = rstart[row+1];
  float acc = 0.f;
  for (int p = s; p < e; ++p)
    acc += csrv[p] * z[(size_t)csrc[p]*32 + lane];
  az[(size_t)row*32 + lane] = acc;
}

// ---------------- decoder + fused cosine-loss accumulation -------------------
__global__ __launch_bounds__(256) void k_dec(const float* __restrict__ az,
    const float* __restrict__ Wdec, const float* __restrict__ x,
    const float* __restrict__ token, float* __restrict__ de,
    float* __restrict__ term_node)
{
  __shared__ float azT[32][36];
  __shared__ float WL[32][132];
  __shared__ float tok[128];
  const int tid = threadIdx.x;
  const int r0 = blockIdx.x * 32;
  {
    int r = tid >> 3, kq = (tid & 7) * 4;
    f32x4 v = *reinterpret_cast<const f32x4*>(&az[(size_t)(r0 + r)*32 + kq]);
    azT[kq+0][r] = v.x; azT[kq+1][r] = v.y; azT[kq+2][r] = v.z; azT[kq+3][r] = v.w;
  }
  const int rg = tid >> 5, cg = tid & 31;
  float srr[4] = {0,0,0,0}, sii[4] = {0,0,0,0}, sri[4] = {0,0,0,0};

  for (int c0 = 0; c0 < 1000; c0 += 128){
    int rem = 1000 - c0; if (rem > 128) rem = 128;
    __syncthreads();
    #pragma unroll
    for (int it = 0; it < 4; ++it){
      int L = it*256 + tid;
      int k = L >> 5, c4 = (L & 31) * 4;
      f32x4 v = {0.f,0.f,0.f,0.f};
      if (c4 < rem) v = *reinterpret_cast<const f32x4*>(&Wdec[(size_t)k*1000 + c0 + c4]);
      *reinterpret_cast<f32x4*>(&WL[k][c4]) = v;
    }
    if (tid < 128){
      int c = c0 + tid;
      tok[tid] = (c < 1000) ? token[c] : 0.f;
    }
    __syncthreads();
    if (cg*4 < rem){
      f32x4 a0 = {0.f,0.f,0.f,0.f}, a1 = a0, a2 = a0, a3 = a0;
      #pragma unroll
      for (int k = 0; k < 32; ++k){
        f32x4 w = *reinterpret_cast<const f32x4*>(&WL[k][cg*4]);
        f32x4 a = *reinterpret_cast<const f32x4*>(&azT[k][rg*4]);
        a0 += a.x * w; a1 += a.y * w; a2 += a.z * w; a3 += a.w * w;
      }
      size_t base = (size_t)(r0 + rg*4)*1000 + c0 + cg*4;
      *reinterpret_cast<f32x4*>(&de[base       ]) = a0;
      *reinterpret_cast<f32x4*>(&de[base + 1000]) = a1;
      *reinterpret_cast<f32x4*>(&de[base + 2000]) = a2;
      *reinterpret_cast<f32x4*>(&de[base + 3000]) = a3;
      // fused loss partials: x_init = x + token
      f32x4 t4 = *reinterpret_cast<const f32x4*>(&tok[cg*4]);
      f32x4 x0 = *reinterpret_cast<const f32x4*>(&x[base       ]);
      f32x4 x1 = *reinterpret_cast<const f32x4*>(&x[base + 1000]);
      f32x4 x2 = *reinterpret_cast<const f32x4*>(&x[base + 2000]);
      f32x4 x3 = *reinterpret_cast<const f32x4*>(&x[base + 3000]);
      x0 += t4; x1 += t4; x2 += t4; x3 += t4;
      srr[0] += a0.x*a0.x + a0.y*a0.y + a0.z*a0.z + a0.w*a0.w;
      srr[1] += a1.x*a1.x + a1.y*a1.y + a1.z*a1.z + a1.w*a1.w;
      srr[2] += a2.x*a2.x + a2.y*a2.y + a2.z*a2.z + a2.w*a2.w;
      srr[3] += a3.x*a3.x + a3.y*a3.y + a3.z*a3.z + a3.w*a3.w;
      sii[0] += x0.x*x0.x + x0.y*x0.y + x0.z*x0.z + x0.w*x0.w;
      sii[1] += x1.x*x1.x + x1.y*x1.y + x1.z*x1.z + x1.w*x1.w;
      sii[2] += x2.x*x2.x + x2.y*x2.y + x2.z*x2.z + x2.w*x2.w;
      sii[3] += x3.x*x3.x + x3.y*x3.y + x3.z*x3.z + x3.w*x3.w;
      sri[0] += a0.x*x0.x + a0.y*x0.y + a0.z*x0.z + a0.w*x0.w;
      sri[1] += a1.x*x1.x + a1.y*x1.y + a1.z*x1.z + a1.w*x1.w;
      sri[2] += a2.x*x2.x + a2.y*x2.y + a2.z*x2.z + a2.w*x2.w;
      sri[3] += a3.x*x3.x + a3.y*x3.y + a3.z*x3.z + a3.w*x3.w;
    }
  }
  // reduce across the 32 col-threads (same half-wave: width 32)
  #pragma unroll
  for (int o = 16; o; o >>= 1){
    #pragma unroll
    for (int rr = 0; rr < 4; ++rr){
      srr[rr] += __shfl_down(srr[rr], o, 32);
      sii[rr] += __shfl_down(sii[rr], o, 32);
      sri[rr] += __shfl_down(sri[rr], o, 32);
    }
  }
  if (cg == 0){
    #pragma unroll
    for (int rr = 0; rr < 4; ++rr){
      int node = r0 + rg*4 + rr;
      float nr = fmaxf(sqrtf(srr[rr]), 1e-12f);
      float ni = fmaxf(sqrtf(sii[rr]), 1e-12f);
      float t = 1.f - sri[rr]/(nr*ni);
      term_node[node] = t*t*t;
    }
  }
}

// ---------------- q (student-t, alpha=1) ------------------------------------
__global__ __launch_bounds__(256) void k_q(const float* __restrict__ z,
    const float* __restrict__ cl, float* __restrict__ q)
{
  __shared__ float cls[320];
  int t = threadIdx.x;
  for (int i = t; i < 320; i += 256) cls[i] = cl[i];
  __syncthreads();
  int row = blockIdx.x*256 + t;
  if (row >= Nn) return;
  float zr[32];
  #pragma unroll
  for (int i = 0; i < 8; ++i){
    f32x4 v = *reinterpret_cast<const f32x4*>(&z[(size_t)row*32 + i*4]);
    zr[i*4] = v.x; zr[i*4+1] = v.y; zr[i*4+2] = v.z; zr[i*4+3] = v.w;
  }
  float qs[10], s = 0.f;
  #pragma unroll
  for (int c = 0; c < 10; ++c){
    float d2 = 0.f;
    #pragma unroll
    for (int k = 0; k < 32; ++k){ float d = zr[k] - cls[c*32 + k]; d2 += d*d; }
    float qq = 1.f/(1.f + d2);
    qs[c] = qq; s += qq;
  }
  float inv = 1.f/s;
  #pragma unroll
  for (int c = 0; c < 10; ++c) q[(size_t)row*10 + c] = qs[c]*inv;
}

// ---------------- loss gather + reduce ---------------------------------------
__global__ __launch_bounds__(256) void k_lpart(const float* __restrict__ term_node,
    const int* __restrict__ mask, float* __restrict__ lpart)
{
  int i = blockIdx.x*256 + threadIdx.x;
  float s = 0.f;
  for (int w = i; w < MM; w += 64*256) s += term_node[mask[w]];
  #pragma unroll
  for (int o = 32; o; o >>= 1) s += __shfl_down(s, o);
  __shared__ float red[4];
  if ((threadIdx.x & 63) == 0) red[threadIdx.x >> 6] = s;
  __syncthreads();
  if (threadIdx.x == 0) lpart[blockIdx.x] = red[0] + red[1] + red[2] + red[3];
}

__global__ __launch_bounds__(64) void k_lsum(const float* __restrict__ lpart,
    float* __restrict__ loss)
{
  float v = lpart[threadIdx.x];
  #pragma unroll
  for (int o = 32; o; o >>= 1) v += __shfl_down(v, o);
  if (threadIdx.x == 0) *loss = v * (1.f/MM);
}

// ---------------- launch -----------------------------------------------------
extern "C" void kernel_launch(void* const* d_in, const int* in_sizes, int n_in,
                              void* d_out, int out_size, void* d_ws, size_t ws_size,
                              hipStream_t stream)
{
  const float* x     = (const float*)d_in[0];
  const int*   erow  = (const int*)  d_in[1];
  const int*   ecol  = (const int*)  d_in[2];
  const float* evls  = (const float*)d_in[3];
  const int*   mask  = (const int*)  d_in[4];
  const float* token = (const float*)d_in[5];
  const float* W1  = (const float*)d_in[6];
  const float* b1  = (const float*)d_in[7];
  const float* g1  = (const float*)d_in[8];
  const float* be1 = (const float*)d_in[9];
  const float* rm1 = (const float*)d_in[10];
  const float* rv1 = (const float*)d_in[11];
  const float* W2  = (const float*)d_in[12];
  const float* b2  = (const float*)d_in[13];
  const float* g2  = (const float*)d_in[14];
  const float* be2 = (const float*)d_in[15];
  const float* rm2 = (const float*)d_in[16];
  const float* rv2 = (const float*)d_in[17];
  const float* Wgc1= (const float*)d_in[18];
  const float* Wgc2= (const float*)d_in[19];
  const float* Wgc3= (const float*)d_in[20];
  const float* Wdec= (const float*)d_in[21];
  const float* clus= (const float*)d_in[22];

  float* out = (float*)d_out;
  float* oz  = out;
  float* omu = out + (size_t)Nn*32;
  float* olv = omu + (size_t)Nn*16;
  float* ode = olv + (size_t)Nn*16;
  float* oq  = ode + (size_t)Nn*1000;
  float* ofx = oq  + (size_t)Nn*10;
  float* ogz = ofx + (size_t)Nn*16;
  float* olo = ogz + (size_t)Nn*16;

  char* w = (char*)d_ws;
  unsigned short* W1t = (unsigned short*)w; w += (size_t)64*KP*2;
  float* tw    = (float*)w; w += 1024;
  int* flags   = (int*)w;   w += (size_t)Nn*4;
  int* deg     = (int*)w;   w += (size_t)Nn*4;
  int* rstart  = (int*)w;   w += (size_t)(Nn+4)*4;
  int* cursor  = (int*)w;   w += (size_t)Nn*4;
  int* bsum    = (int*)w;   w += 1024;
  int* csrc    = (int*)w;   w += (size_t)Ee*4;
  float* csrv  = (float*)w; w += (size_t)Ee*4;
  float* afx   = (float*)w; w += (size_t)Nn*16*4;
  float* h1    = (float*)w; w += (size_t)Nn*64*4;
  float* ah    = (float*)w; w += (size_t)Nn*64*4;
  float* az    = (float*)w; w += (size_t)Nn*32*4;
  float* term_node = (float*)w; w += (size_t)Nn*4;
  float* lpart = (float*)w; w += 1024;

  k_init<<<dim3(313), dim3(256), 0, stream>>>(W1, token, W1t, tw, flags, deg);
  k_scatter<<<dim3((Ee+255)/256), dim3(256), 0, stream>>>(mask, erow, flags, deg);
  k_scan1<<<dim3(NB), dim3(256), 0, stream>>>(deg, bsum);
  k_scan2<<<dim3(1), dim3(128), 0, stream>>>(bsum, rstart);
  k_scan3<<<dim3(NB), dim3(256), 0, stream>>>(deg, bsum, rstart, cursor);
  k_fill<<<dim3((Ee+255)/256), dim3(256), 0, stream>>>(erow, ecol, evls, cursor, csrc, csrv);
  k_gemm1<<<dim3(Nn/128), dim3(256), 0, stream>>>(x, W1t, flags, tw,
      b1, g1, be1, rm1, rv1, W2, b2, g2, be2, rm2, rv2, ofx);
  k_spmm16<<<dim3(Nn/16), dim3(256), 0, stream>>>(rstart, csrc, csrv, ofx, afx);
  k_h1<<<dim3((Nn*64+255)/256), dim3(256), 0, stream>>>(afx, Wgc1, h1);
  k_spmm64<<<dim3(Nn/4), dim3(256), 0, stream>>>(rstart, csrc, csrv, h1, ah);
  k_mulv<<<dim3((Nn*16+255)/256), dim3(256), 0, stream>>>(ah, Wgc2, Wgc3, ofx, oz, omu, olv, ogz);
  k_spmm32<<<dim3(Nn/8), dim3(256), 0, stream>>>(rstart, csrc, csrv, oz, az);
  k_dec<<<dim3(Nn/32), dim3(256), 0, stream>>>(az, Wdec, x, token, ode, term_node);
  k_q<<<dim3((Nn+255)/256), dim3(256), 0, stream>>>(oz, clus, oq);
  k_lpart<<<dim3(64), dim3(256), 0, stream>>>(term_node, mask, lpart);
  k_lsum<<<dim3(1), dim3(64), 0, stream>>>(lpart, olo);
}